// Round 1
// 886.680 us; speedup vs baseline: 1.1220x; 1.1220x over previous
//
#include <hip/hip_runtime.h>
#include <cstdint>
#include <cstddef>

#define H_   512
#define W_   1024
#define HP_  256
#define WP_  512
#define NTAP 9
#define CIN  128
#define COUT 64
#define HWP  (HP_*WP_)      /* 131072 */
#define MIDX (HWP*NTAP)     /* 1179648 */
#define HW_  (H_*W_)        /* 524288 */

typedef __attribute__((ext_vector_type(8))) short bhalf8_t;
typedef __attribute__((ext_vector_type(4))) float floatx4_t;

__device__ __forceinline__ unsigned short f2bf(float f) {
    unsigned u = __float_as_uint(f);
    u += 0x7fffu + ((u >> 16) & 1u);
    return (unsigned short)(u >> 16);
}
__device__ __forceinline__ float bf2f(unsigned short s) {
    return __uint_as_float(((unsigned)s) << 16);
}

// ---------------- K0: fold w_post into w_conv (W' = w_post @ w_conv per tap), bf16;
//                  fold splat_bias/b_post into sb2; zero stat accumulators ------------
__global__ __launch_bounds__(256) void k0_prep(
    const float* __restrict__ w_conv, const float* __restrict__ w_post,
    const float* __restrict__ sbias,  const float* __restrict__ b_post,
    unsigned short* __restrict__ w2, float* __restrict__ sb2,
    float* __restrict__ gnzero /*256 floats: gnsum1+gnsum2*/) {
    int idx = blockIdx.x * 256 + threadIdx.x;
    if (idx < 73728) {                       // 576*128 folded weights, w2 row = n*64+o
        int r = idx >> 7, ci = idx & 127;
        int n = r >> 6, o = r & 63;
        float acc = 0.f;
        #pragma unroll 8
        for (int op = 0; op < 64; ++op)
            acc = fmaf(w_post[o*64 + op], w_conv[(op*9 + n)*128 + ci], acc);
        w2[idx] = f2bf(acc);
    } else if (idx < 73728 + 64) {           // sb2[o] = w_post @ splat_bias + b_post
        int o = idx - 73728;
        float acc = b_post[o];
        for (int op = 0; op < 64; ++op)
            acc = fmaf(w_post[o*64 + op], sbias[op], acc);
        sb2[o] = acc;
    } else if (idx < 73728 + 64 + 256) {
        gnzero[idx - (73728 + 64)] = 0.f;
    }
}

// ---------------- K1: GroupNorm1 partial stats (atomic accumulate per (b,g)) ----------
__global__ __launch_bounds__(256) void k1_stats(const float* __restrict__ x,
                                                float* __restrict__ gnsum1) {
    __shared__ float red[512];
    int bid = blockIdx.x;                 // 512 blocks: (b, g, slice)
    int b = bid >> 8, rem = bid & 255;
    int g = rem >> 3, slice = rem & 7;
    const float4* xp = (const float4*)x + (size_t)(b*CIN + g*4) * (HWP/4) + (size_t)slice*16384;
    float s = 0.f, s2 = 0.f;
    for (int i = threadIdx.x; i < 16384; i += 256) {
        float4 v = xp[i];
        s  += v.x + v.y + v.z + v.w;
        s2 += v.x*v.x + v.y*v.y + v.z*v.z + v.w*v.w;
    }
    red[threadIdx.x] = s; red[256 + threadIdx.x] = s2;
    __syncthreads();
    for (int off = 128; off > 0; off >>= 1) {
        if (threadIdx.x < off) {
            red[threadIdx.x] += red[threadIdx.x + off];
            red[256 + threadIdx.x] += red[256 + threadIdx.x + off];
        }
        __syncthreads();
    }
    if (threadIdx.x == 0) {
        atomicAdd(&gnsum1[(b*32 + g)*2],     red[0]);
        atomicAdd(&gnsum1[(b*32 + g)*2 + 1], red[256]);
    }
}

// ---------------- K1b: finalize GN1 -> per (b,c) affine coefficients -----------------
__global__ void k1b_coef(const float* __restrict__ gnsum1,
                         const float* __restrict__ gamma1, const float* __restrict__ beta1,
                         float* __restrict__ acoef, float* __restrict__ bcoef) {
    int t = threadIdx.x;                 // 256 = 2*128
    int b = t >> 7, c = t & 127, g = c >> 2;
    float s1 = gnsum1[(b*32+g)*2], s2 = gnsum1[(b*32+g)*2+1];
    const float inv = 1.f / 524288.f;
    float mean = s1 * inv;
    float var  = s2 * inv - mean*mean;
    float rstd = rsqrtf(var + 1e-5f);
    float a = gamma1[c] * rstd;
    acoef[t] = a;
    bcoef[t] = beta1[c] - mean * a;
}

// ---------------- K2: normalized 1x1 conv via MFMA -> vals[b][p][n][o] bf16 ----------
__global__ __launch_bounds__(256) void k2_conv(
    const float* __restrict__ x, const unsigned short* __restrict__ w2,
    const float* __restrict__ acoef, const float* __restrict__ bcoef,
    unsigned short* __restrict__ vals) {
    __shared__ unsigned short As[64*136];   // w2 tile [o][k], pad 8
    __shared__ unsigned short Bs[128*136];  // xnorm tile [p][k], pad 8
    __shared__ unsigned short Cs[128*72];   // out stage [p][o], pad 8
    int b   = blockIdx.y;
    int tile = blockIdx.x;                  // 1024: pr*4 + pc-quarter
    int pr  = tile >> 2, pcb = (tile & 3) << 7;
    int tid = threadIdx.x;

    // stage Bs: 128 p x 128 c, normalize on the fly, bf16, b128 LDS writes
    for (int task = tid; task < 2048; task += 256) {
        int p = task & 127, c0 = (task >> 7) << 3;
        bhalf8_t t8;
        #pragma unroll
        for (int j = 0; j < 8; ++j) {
            int c = c0 + j;
            float xv = x[(size_t)(b*CIN + c)*HWP + (size_t)pr*WP_ + pcb + p];
            float v = fmaf(xv, acoef[b*CIN + c], bcoef[b*CIN + c]);
            t8[j] = (short)f2bf(v);
        }
        *(bhalf8_t*)&Bs[p*136 + c0] = t8;
    }
    __syncthreads();

    int wave = tid >> 6, lane = tid & 63;
    int l15 = lane & 15, lq = lane >> 4;

    // hoist B fragments (identical across all 9 M-tiles)
    bhalf8_t bfr[2][4];
    #pragma unroll
    for (int ptl = 0; ptl < 2; ++ptl) {
        int p = (wave*2 + ptl)*16 + l15;
        #pragma unroll
        for (int ks = 0; ks < 4; ++ks)
            bfr[ptl][ks] = *(const bhalf8_t*)&Bs[p*136 + ks*32 + lq*8];
    }

    for (int n = 0; n < 9; ++n) {
        __syncthreads();
        for (int i = tid; i < 4096; i += 256) {          // stage As (uint copy)
            int r = i >> 6, cp = i & 63;
            ((unsigned*)As)[r*68 + cp] = ((const unsigned*)w2)[(n*64 + r)*64 + cp];
        }
        __syncthreads();
        floatx4_t acc[2][4] = {};
        #pragma unroll
        for (int ks = 0; ks < 4; ++ks) {
            bhalf8_t af[4];
            #pragma unroll
            for (int rt = 0; rt < 4; ++rt)
                af[rt] = *(const bhalf8_t*)&As[(rt*16 + l15)*136 + ks*32 + lq*8];
            #pragma unroll
            for (int ptl = 0; ptl < 2; ++ptl)
                #pragma unroll
                for (int rt = 0; rt < 4; ++rt)
                    acc[ptl][rt] = __builtin_amdgcn_mfma_f32_16x16x32_bf16(
                        af[rt], bfr[ptl][ks], acc[ptl][rt], 0, 0, 0);
        }
        // acc -> Cs  (D layout: col(lane&15)=p, row(quad*4+reg)=o)
        #pragma unroll
        for (int ptl = 0; ptl < 2; ++ptl) {
            int p = (wave*2 + ptl)*16 + l15;
            #pragma unroll
            for (int rt = 0; rt < 4; ++rt)
                #pragma unroll
                for (int reg = 0; reg < 4; ++reg) {
                    int o = rt*16 + lq*4 + reg;
                    Cs[p*72 + o] = f2bf(acc[ptl][rt][reg]);
                }
        }
        __syncthreads();
        size_t outbase = (size_t)b*HWP + (size_t)pr*WP_ + pcb;
        for (int i = tid; i < 4096; i += 256) {          // coalesced uint store
            int p = i >> 5, o2 = i & 31;
            ((unsigned*)vals)[((outbase + p)*576 + n*64)/2 + o2] = ((const unsigned*)Cs)[p*36 + o2];
        }
    }
}

// ---------------- K3: gather-splat + normalize + sb2 + GN2 stats (no MFMA) -----------
__global__ __launch_bounds__(256) void k3_gather(
    const float* __restrict__ gridp, const unsigned short* __restrict__ vals,
    const float* __restrict__ sb2g,
    float* __restrict__ out, float* __restrict__ gnsum2) {

    __shared__ float sb2_s[64];
    __shared__ float red[256];

    int tid = threadIdx.x;
    int bx = blockIdx.x;        // 0..3  (x-tile of 256)
    int y  = blockIdx.y;        // 0..511
    int b  = blockIdx.z;        // 0..1
    int x  = (bx << 8) + tid;

    if (tid < 64) sb2_s[tid] = sb2g[tid];
    __syncthreads();

    float num[64];
    #pragma unroll
    for (int c = 0; c < 64; ++c) num[c] = 0.f;
    float den = 0.f;

    const float2* g2 = (const float2*)gridp;
    int prc = y >> 1;
    for (int dpr = -1; dpr <= 1; ++dpr) {
        int pr = prc + dpr;
        if (pr < 0 || pr > HP_-1) continue;
        for (int kyi = 0; kyi < 3; ++kyi) {
            // row geometry (pc-invariant bitwise): read at pc=0, kx=0
            float gy = g2[pr*WP_*9 + kyi*3 + 1].y;
            float py = ((gy + 1.0f) * 0.5f) * 511.0f;
            float y0f = floorf(py);
            float fy = py - y0f;
            int y0i = (int)y0f;
            #pragma unroll
            for (int side = 0; side < 2; ++side) {
                int yi = y0i + side;
                bool pn = yi < 0, ps = yi >= H_;
                int yy = pn ? -yi : (ps ? (2*H_ - yi) : yi);
                yy = min(max(yy, 0), H_-1);
                if (yy != y) continue;
                int sh = (pn || ps) ? (W_/2) : 0;
                float wy = side ? fy : (1.0f - fy);
                for (int kxi = 0; kxi < 3; ++kxi) {
                    int n = kyi*3 + kxi;
                    float gx0 = g2[pr*WP_*9 + n].x;
                    float px0 = ((gx0 + 1.0f) * 0.5f) * 1023.0f;  // model: px(pc)=px0+2pc
                    int Tt = x - sh - 1;
                    #pragma unroll
                    for (int j = -1; j <= 1; ++j) {
                        float A = ((float)(Tt + j*W_) - px0) * 0.5f;
                        int clo = (int)ceilf(A - 1e-3f);
                        int chi = (int)floorf(A + 1.001f);
                        for (int pc = clo; pc <= chi; ++pc) {
                            if (pc < 0 || pc >= WP_) continue;
                            int m = (pr*WP_ + pc)*9 + n;
                            float2 g = g2[m];
                            float px = ((g.x + 1.0f) * 0.5f) * 1023.0f;  // exact ref arith
                            float x0f = floorf(px);
                            float fx = px - x0f;
                            int x0i = (int)x0f;
                            int xl = (x0i + 2*W_ + sh) & (W_-1);
                            float w;
                            if (xl == x)                      w = (1.0f - fx) * wy;
                            else if (((xl + 1) & (W_-1)) == x) w = fx * wy;
                            else continue;
                            den += w;
                            const uint4* vp = (const uint4*)(vals + (((size_t)b*MIDX + m) << 6));
                            #pragma unroll
                            for (int q = 0; q < 8; ++q) {
                                uint4 u = vp[q];
                                unsigned uu[4] = {u.x, u.y, u.z, u.w};
                                #pragma unroll
                                for (int e = 0; e < 4; ++e) {
                                    float lo = __uint_as_float(uu[e] << 16);
                                    float hi = __uint_as_float(uu[e] & 0xffff0000u);
                                    num[q*8 + e*2]     = fmaf(w, lo, num[q*8 + e*2]);
                                    num[q*8 + e*2 + 1] = fmaf(w, hi, num[q*8 + e*2 + 1]);
                                }
                            }
                        }
                    }
                }
            }
        }
    }

    // epilogue: v = num/den + sb2 (post-conv already folded); coalesced fp32 store
    float invd = 1.0f / fmaxf(den, 1e-8f);
    size_t obase = ((size_t)b << 25) + ((size_t)y << 10) + (size_t)x;
    #pragma unroll
    for (int c = 0; c < 64; ++c) {
        float v = fmaf(num[c], invd, sb2_s[c]);
        out[obase + ((size_t)c << 19)] = v;
        num[c] = v;
    }

    // GN2 stats: st[g]=sum over the 2 channels of group g; st[32+g]=sum of squares
    float st[64];
    #pragma unroll
    for (int g = 0; g < 32; ++g) {
        float a = num[2*g], b2 = num[2*g + 1];
        st[g]      = a + b2;
        st[32 + g] = fmaf(a, a, b2*b2);
    }
    int lane = tid & 63;
    // recursive-halving reduce-scatter across the wave: lane l ends owning stat l
    float r32[32];
    { bool hi = (lane & 32) != 0;
      #pragma unroll
      for (int j = 0; j < 32; ++j) {
          float keep = hi ? st[32+j] : st[j];
          float send = hi ? st[j]    : st[32+j];
          r32[j] = keep + __shfl_xor(send, 32, 64);
      } }
    float r16[16];
    { bool hi = (lane & 16) != 0;
      #pragma unroll
      for (int j = 0; j < 16; ++j) {
          float keep = hi ? r32[16+j] : r32[j];
          float send = hi ? r32[j]    : r32[16+j];
          r16[j] = keep + __shfl_xor(send, 16, 64);
      } }
    float r8[8];
    { bool hi = (lane & 8) != 0;
      #pragma unroll
      for (int j = 0; j < 8; ++j) {
          float keep = hi ? r16[8+j] : r16[j];
          float send = hi ? r16[j]   : r16[8+j];
          r8[j] = keep + __shfl_xor(send, 8, 64);
      } }
    float r4[4];
    { bool hi = (lane & 4) != 0;
      #pragma unroll
      for (int j = 0; j < 4; ++j) {
          float keep = hi ? r8[4+j] : r8[j];
          float send = hi ? r8[j]   : r8[4+j];
          r4[j] = keep + __shfl_xor(send, 4, 64);
      } }
    float r2[2];
    { bool hi = (lane & 2) != 0;
      #pragma unroll
      for (int j = 0; j < 2; ++j) {
          float keep = hi ? r4[2+j] : r4[j];
          float send = hi ? r4[j]   : r4[2+j];
          r2[j] = keep + __shfl_xor(send, 2, 64);
      } }
    float r1;
    { bool hi = (lane & 1) != 0;
      float keep = hi ? r2[1] : r2[0];
      float send = hi ? r2[0] : r2[1];
      r1 = keep + __shfl_xor(send, 1, 64);
    }
    red[tid] = r1;                        // tid = wave*64 + lane
    __syncthreads();
    if (tid < 64) {
        float tot = red[tid] + red[tid + 64] + red[tid + 128] + red[tid + 192];
        int slot = (tid < 32) ? (tid << 1) : (((tid - 32) << 1) + 1);
        atomicAdd(&gnsum2[(b << 6) + slot], tot);
    }
}

// ---------------- K5: in-place GroupNorm2 + exact GELU on d_out ----------------------
__global__ __launch_bounds__(256) void k5_final(
    float* __restrict__ out, const float* __restrict__ gnsum2,
    const float* __restrict__ gamma2, const float* __restrict__ beta2) {
    size_t idx = (size_t)blockIdx.x * 256 + threadIdx.x;   // 8388608 threads, 8 elems each
    size_t e8 = idx << 3;
    int b = (int)(e8 >> 25);
    int o = (int)((e8 >> 19) & 63);
    int g = o >> 1;
    float s1 = gnsum2[b*64 + g*2], s2 = gnsum2[b*64 + g*2 + 1];
    const float invn = 1.0f / 1048576.0f;
    float mean = s1 * invn;
    float var  = s2 * invn - mean*mean;
    float rstd = rsqrtf(var + 1e-5f);
    float sc = gamma2[o] * rstd;
    float sf = beta2[o] - mean * sc;
    float4* p0 = (float4*)(out + e8);
    float4 v0 = p0[0], v1 = p0[1];
    float r[8] = {v0.x, v0.y, v0.z, v0.w, v1.x, v1.y, v1.z, v1.w};
    #pragma unroll
    for (int j = 0; j < 8; ++j) {
        float t = fmaf(r[j], sc, sf);
        r[j] = 0.5f * t * (1.0f + erff(t * 0.70710678118654752f));
    }
    p0[0] = make_float4(r[0], r[1], r[2], r[3]);
    p0[1] = make_float4(r[4], r[5], r[6], r[7]);
}

// -------------------------------------------------------------------------------------
extern "C" void kernel_launch(void* const* d_in, const int* in_sizes, int n_in,
                              void* d_out, int out_size, void* d_ws, size_t ws_size,
                              hipStream_t stream) {
    const float* x      = (const float*)d_in[0];
    const float* gridp  = (const float*)d_in[1];
    const float* gamma1 = (const float*)d_in[2];
    const float* beta1  = (const float*)d_in[3];
    const float* w_conv = (const float*)d_in[4];
    const float* sbias  = (const float*)d_in[5];
    const float* w_post = (const float*)d_in[6];
    const float* b_post = (const float*)d_in[7];
    const float* gamma2 = (const float*)d_in[8];
    const float* beta2  = (const float*)d_in[9];
    float* out = (float*)d_out;

    char* ws = (char*)d_ws;
    unsigned short* w2 = (unsigned short*)(ws);                      // 147456 B
    float* gnsum1 = (float*)(ws + 147456);                           // 512 B
    float* gnsum2 = (float*)(ws + 147968);                           // 512 B (contig w/ gnsum1)
    float* acoef  = (float*)(ws + 148480);                           // 1024 B
    float* bcoef  = (float*)(ws + 149504);                           // 1024 B
    float* sb2    = (float*)(ws + 150528);                           // 256 B
    unsigned short* vals = (unsigned short*)(ws + 150784);           // 301,989,888 B
    // total ws needed: 302,140,672 B (~288 MiB)

    hipLaunchKernelGGL(k0_prep,  dim3(290),          dim3(256), 0, stream,
                       w_conv, w_post, sbias, b_post, w2, sb2, gnsum1);
    hipLaunchKernelGGL(k1_stats, dim3(512),          dim3(256), 0, stream, x, gnsum1);
    hipLaunchKernelGGL(k1b_coef, dim3(1),            dim3(256), 0, stream,
                       gnsum1, gamma1, beta1, acoef, bcoef);
    hipLaunchKernelGGL(k2_conv,  dim3(1024, 2),      dim3(256), 0, stream,
                       x, w2, acoef, bcoef, vals);
    hipLaunchKernelGGL(k3_gather, dim3(4, 512, 2),   dim3(256), 0, stream,
                       gridp, vals, sb2, out, gnsum2);
    hipLaunchKernelGGL(k5_final, dim3(32768),        dim3(256), 0, stream,
                       out, gnsum2, gamma2, beta2);
}

// Round 2
// 848.137 us; speedup vs baseline: 1.1729x; 1.0454x over previous
//
#include <hip/hip_runtime.h>
#include <cstdint>
#include <cstddef>

#define H_   512
#define W_   1024
#define HP_  256
#define WP_  512
#define NTAP 9
#define CIN  128
#define COUT 64
#define HWP  (HP_*WP_)      /* 131072 */
#define MIDX (HWP*NTAP)     /* 1179648 */
#define HW_  (H_*W_)        /* 524288 */

typedef __attribute__((ext_vector_type(8))) short bhalf8_t;
typedef __attribute__((ext_vector_type(4))) float floatx4_t;

__device__ __forceinline__ unsigned short f2bf(float f) {
    unsigned u = __float_as_uint(f);
    u += 0x7fffu + ((u >> 16) & 1u);
    return (unsigned short)(u >> 16);
}
__device__ __forceinline__ unsigned cvt_pk_bf16(float lo, float hi) {
    unsigned r;
    asm("v_cvt_pk_bf16_f32 %0, %1, %2" : "=v"(r) : "v"(lo), "v"(hi));
    return r;
}

// ---------------- K0: fold w_post into w_conv (fp32), sb2, zero stat accumulators ----
__global__ __launch_bounds__(256) void k0_prep(
    const float* __restrict__ w_conv, const float* __restrict__ w_post,
    const float* __restrict__ sbias,  const float* __restrict__ b_post,
    float* __restrict__ wfold, float* __restrict__ sb2,
    float* __restrict__ gnzero /*256 floats: gnsum1+gnsum2*/) {
    int idx = blockIdx.x * 256 + threadIdx.x;
    if (idx < 73728) {                       // 576*128 folded weights, row = n*64+o
        int r = idx >> 7, ci = idx & 127;
        int n = r >> 6, o = r & 63;
        float acc = 0.f;
        #pragma unroll 8
        for (int op = 0; op < 64; ++op)
            acc = fmaf(w_post[o*64 + op], w_conv[(op*9 + n)*128 + ci], acc);
        wfold[idx] = acc;
    } else if (idx < 73728 + 64) {           // sb2[o] = w_post @ splat_bias + b_post
        int o = idx - 73728;
        float acc = b_post[o];
        for (int op = 0; op < 64; ++op)
            acc = fmaf(w_post[o*64 + op], sbias[op], acc);
        sb2[o] = acc;
    } else if (idx < 73728 + 64 + 256) {
        gnzero[idx - (73728 + 64)] = 0.f;
    }
}

// ---------------- K1: GroupNorm1 partial stats (atomic accumulate per (b,g)) ----------
__global__ __launch_bounds__(256) void k1_stats(const float* __restrict__ x,
                                                float* __restrict__ gnsum1) {
    __shared__ float red[512];
    int bid = blockIdx.x;                 // 512 blocks: (b, g, slice)
    int b = bid >> 8, rem = bid & 255;
    int g = rem >> 3, slice = rem & 7;
    const float4* xp = (const float4*)x + (size_t)(b*CIN + g*4) * (HWP/4) + (size_t)slice*16384;
    float s = 0.f, s2 = 0.f;
    for (int i = threadIdx.x; i < 16384; i += 256) {
        float4 v = xp[i];
        s  += v.x + v.y + v.z + v.w;
        s2 += v.x*v.x + v.y*v.y + v.z*v.z + v.w*v.w;
    }
    red[threadIdx.x] = s; red[256 + threadIdx.x] = s2;
    __syncthreads();
    for (int off = 128; off > 0; off >>= 1) {
        if (threadIdx.x < off) {
            red[threadIdx.x] += red[threadIdx.x + off];
            red[256 + threadIdx.x] += red[256 + threadIdx.x + off];
        }
        __syncthreads();
    }
    if (threadIdx.x == 0) {
        atomicAdd(&gnsum1[(b*32 + g)*2],     red[0]);
        atomicAdd(&gnsum1[(b*32 + g)*2 + 1], red[256]);
    }
}

// ---------------- K1b: finalize GN1 -> per (b,c) affine coefficients -----------------
__global__ void k1b_coef(const float* __restrict__ gnsum1,
                         const float* __restrict__ gamma1, const float* __restrict__ beta1,
                         float* __restrict__ acoef, float* __restrict__ bcoef) {
    int t = threadIdx.x;                 // 256 = 2*128
    int b = t >> 7, c = t & 127, g = c >> 2;
    float s1 = gnsum1[(b*32+g)*2], s2 = gnsum1[(b*32+g)*2+1];
    const float inv = 1.f / 524288.f;
    float mean = s1 * inv;
    float var  = s2 * inv - mean*mean;
    float rstd = rsqrtf(var + 1e-5f);
    float a = gamma1[c] * rstd;
    acoef[t] = a;
    bcoef[t] = beta1[c] - mean * a;
}

// ---------------- K1c: per-batch scaled weights (bf16) + folded GN1 bias -------------
__global__ __launch_bounds__(256) void k1c_scale(
    const float* __restrict__ wfold, const float* __restrict__ acoef,
    const float* __restrict__ bcoef,
    unsigned short* __restrict__ w2b, float* __restrict__ vb) {
    int b = blockIdx.y;
    int idx = blockIdx.x * 256 + threadIdx.x;
    if (idx < 73728) {                       // W''[b] = W' * a[b][c]
        int c = idx & 127;
        w2b[b*73728 + idx] = f2bf(wfold[idx] * acoef[b*128 + c]);
    } else if (idx < 73728 + 576) {          // vb[b][r] = sum_c W'[r][c]*bcoef[b][c]
        int r = idx - 73728;
        float acc = 0.f;
        #pragma unroll 8
        for (int c = 0; c < 128; ++c)
            acc = fmaf(wfold[r*128 + c], bcoef[b*128 + c], acc);
        vb[b*576 + r] = acc;
    }
}

// ---------------- K2: raw-x 1x1 conv via MFMA, A direct from L2 -> vals bf16 ---------
__global__ __launch_bounds__(256) void k2_conv(
    const float* __restrict__ x, const unsigned short* __restrict__ w2b,
    const float* __restrict__ vb,
    unsigned short* __restrict__ vals) {
    __shared__ unsigned short Bs[128*136];  // raw x tile bf16 [p][c], pad 8
    __shared__ unsigned short Cs[128*72];   // out stage [p][o], pad 8
    int b   = blockIdx.y;
    int tile = blockIdx.x;                  // 1024: pr*4 + pc-quarter
    int pr  = tile >> 2, pcb = (tile & 3) << 7;
    int tid = threadIdx.x;

    // stage Bs: 128 p x 128 c raw x -> bf16 (cvt_pk), b128 LDS writes
    for (int task = tid; task < 2048; task += 256) {
        int p = task & 127, c0 = (task >> 7) << 3;
        const float* xp = &x[(size_t)(b*CIN + c0)*HWP + (size_t)pr*WP_ + pcb + p];
        float v0 = xp[0];
        float v1 = xp[HWP];
        float v2 = xp[2*HWP];
        float v3 = xp[3*HWP];
        float v4 = xp[4*HWP];
        float v5 = xp[5*HWP];
        float v6 = xp[6*HWP];
        float v7 = xp[7*HWP];
        uint4 t;
        t.x = cvt_pk_bf16(v0, v1);
        t.y = cvt_pk_bf16(v2, v3);
        t.z = cvt_pk_bf16(v4, v5);
        t.w = cvt_pk_bf16(v6, v7);
        *(uint4*)&Bs[p*136 + c0] = t;
    }
    __syncthreads();

    int wave = tid >> 6, lane = tid & 63;
    int l15 = lane & 15, lq = lane >> 4;

    // hoist B fragments (identical across all 9 taps)
    bhalf8_t bfr[2][4];
    #pragma unroll
    for (int ptl = 0; ptl < 2; ++ptl) {
        int p = (wave*2 + ptl)*16 + l15;
        #pragma unroll
        for (int ks = 0; ks < 4; ++ks)
            bfr[ptl][ks] = *(const bhalf8_t*)&Bs[p*136 + ks*32 + lq*8];
    }

    const unsigned short* wb = w2b + (size_t)b*73728;
    const float* vbb = vb + b*576;

    for (int n = 0; n < 9; ++n) {
        // acc init from folded GN1 bias (broadcast over p)
        floatx4_t acc[2][4];
        #pragma unroll
        for (int rt = 0; rt < 4; ++rt) {
            float4 vbv = *(const float4*)&vbb[n*64 + rt*16 + lq*4];
            floatx4_t a0; a0[0] = vbv.x; a0[1] = vbv.y; a0[2] = vbv.z; a0[3] = vbv.w;
            acc[0][rt] = a0; acc[1][rt] = a0;
        }
        // MFMA, A-fragments direct from L2-resident w2b
        #pragma unroll
        for (int ks = 0; ks < 4; ++ks) {
            bhalf8_t af[4];
            #pragma unroll
            for (int rt = 0; rt < 4; ++rt)
                af[rt] = *(const bhalf8_t*)&wb[(n*64 + rt*16 + l15)*128 + ks*32 + lq*8];
            #pragma unroll
            for (int ptl = 0; ptl < 2; ++ptl)
                #pragma unroll
                for (int rt = 0; rt < 4; ++rt)
                    acc[ptl][rt] = __builtin_amdgcn_mfma_f32_16x16x32_bf16(
                        af[rt], bfr[ptl][ks], acc[ptl][rt], 0, 0, 0);
        }
        __syncthreads();   // previous store-loop finished reading Cs
        // acc -> Cs via cvt_pk + b64 writes (D layout: col(l15)=p, row(lq*4+reg)=o)
        #pragma unroll
        for (int ptl = 0; ptl < 2; ++ptl) {
            int p = (wave*2 + ptl)*16 + l15;
            #pragma unroll
            for (int rt = 0; rt < 4; ++rt) {
                uint2 d;
                d.x = cvt_pk_bf16(acc[ptl][rt][0], acc[ptl][rt][1]);
                d.y = cvt_pk_bf16(acc[ptl][rt][2], acc[ptl][rt][3]);
                *(uint2*)&Cs[p*72 + rt*16 + lq*4] = d;
            }
        }
        __syncthreads();
        size_t outbase = (size_t)b*HWP + (size_t)pr*WP_ + pcb;
        for (int i = tid; i < 4096; i += 256) {          // coalesced uint store
            int p = i >> 5, o2 = i & 31;
            ((unsigned*)vals)[((outbase + p)*576 + n*64)/2 + o2] = ((const unsigned*)Cs)[p*36 + o2];
        }
    }
}

// ---------------- K3: gather-splat + normalize + sb2 + GN2 stats (no MFMA) -----------
__global__ __launch_bounds__(256) void k3_gather(
    const float* __restrict__ gridp, const unsigned short* __restrict__ vals,
    const float* __restrict__ sb2g,
    float* __restrict__ out, float* __restrict__ gnsum2) {

    __shared__ float sb2_s[64];
    __shared__ float red[256];

    int tid = threadIdx.x;
    int bx = blockIdx.x;        // 0..3  (x-tile of 256)
    int y  = blockIdx.y;        // 0..511
    int b  = blockIdx.z;        // 0..1
    int x  = (bx << 8) + tid;

    if (tid < 64) sb2_s[tid] = sb2g[tid];
    __syncthreads();

    float num[64];
    #pragma unroll
    for (int c = 0; c < 64; ++c) num[c] = 0.f;
    float den = 0.f;

    const float2* g2 = (const float2*)gridp;
    int prc = y >> 1;
    for (int dpr = -1; dpr <= 1; ++dpr) {
        int pr = prc + dpr;
        if (pr < 0 || pr > HP_-1) continue;
        for (int kyi = 0; kyi < 3; ++kyi) {
            // row geometry (pc-invariant bitwise): read at pc=0, kx=0
            float gy = g2[pr*WP_*9 + kyi*3 + 1].y;
            float py = ((gy + 1.0f) * 0.5f) * 511.0f;
            float y0f = floorf(py);
            float fy = py - y0f;
            int y0i = (int)y0f;
            #pragma unroll
            for (int side = 0; side < 2; ++side) {
                int yi = y0i + side;
                bool pn = yi < 0, ps = yi >= H_;
                int yy = pn ? -yi : (ps ? (2*H_ - yi) : yi);
                yy = min(max(yy, 0), H_-1);
                if (yy != y) continue;
                int sh = (pn || ps) ? (W_/2) : 0;
                float wy = side ? fy : (1.0f - fy);
                for (int kxi = 0; kxi < 3; ++kxi) {
                    int n = kyi*3 + kxi;
                    float gx0 = g2[pr*WP_*9 + n].x;
                    float px0 = ((gx0 + 1.0f) * 0.5f) * 1023.0f;  // model: px(pc)=px0+2pc
                    int Tt = x - sh - 1;
                    #pragma unroll
                    for (int j = -1; j <= 1; ++j) {
                        float A = ((float)(Tt + j*W_) - px0) * 0.5f;
                        int clo = (int)ceilf(A - 1e-3f);
                        int chi = (int)floorf(A + 1.001f);
                        for (int pc = clo; pc <= chi; ++pc) {
                            if (pc < 0 || pc >= WP_) continue;
                            int m = (pr*WP_ + pc)*9 + n;
                            float2 g = g2[m];
                            float px = ((g.x + 1.0f) * 0.5f) * 1023.0f;  // exact ref arith
                            float x0f = floorf(px);
                            float fx = px - x0f;
                            int x0i = (int)x0f;
                            int xl = (x0i + 2*W_ + sh) & (W_-1);
                            float w;
                            if (xl == x)                      w = (1.0f - fx) * wy;
                            else if (((xl + 1) & (W_-1)) == x) w = fx * wy;
                            else continue;
                            den += w;
                            const uint4* vp = (const uint4*)(vals + (((size_t)b*MIDX + m) << 6));
                            #pragma unroll
                            for (int q = 0; q < 8; ++q) {
                                uint4 u = vp[q];
                                unsigned uu[4] = {u.x, u.y, u.z, u.w};
                                #pragma unroll
                                for (int e = 0; e < 4; ++e) {
                                    float lo = __uint_as_float(uu[e] << 16);
                                    float hi = __uint_as_float(uu[e] & 0xffff0000u);
                                    num[q*8 + e*2]     = fmaf(w, lo, num[q*8 + e*2]);
                                    num[q*8 + e*2 + 1] = fmaf(w, hi, num[q*8 + e*2 + 1]);
                                }
                            }
                        }
                    }
                }
            }
        }
    }

    // epilogue: v = num/den + sb2 (post-conv already folded); coalesced fp32 store
    float invd = 1.0f / fmaxf(den, 1e-8f);
    size_t obase = ((size_t)b << 25) + ((size_t)y << 10) + (size_t)x;
    #pragma unroll
    for (int c = 0; c < 64; ++c) {
        float v = fmaf(num[c], invd, sb2_s[c]);
        out[obase + ((size_t)c << 19)] = v;
        num[c] = v;
    }

    // GN2 stats: st[g]=sum over the 2 channels of group g; st[32+g]=sum of squares
    float st[64];
    #pragma unroll
    for (int g = 0; g < 32; ++g) {
        float a = num[2*g], b2 = num[2*g + 1];
        st[g]      = a + b2;
        st[32 + g] = fmaf(a, a, b2*b2);
    }
    int lane = tid & 63;
    // recursive-halving reduce-scatter across the wave: lane l ends owning stat l
    float r32[32];
    { bool hi = (lane & 32) != 0;
      #pragma unroll
      for (int j = 0; j < 32; ++j) {
          float keep = hi ? st[32+j] : st[j];
          float send = hi ? st[j]    : st[32+j];
          r32[j] = keep + __shfl_xor(send, 32, 64);
      } }
    float r16[16];
    { bool hi = (lane & 16) != 0;
      #pragma unroll
      for (int j = 0; j < 16; ++j) {
          float keep = hi ? r32[16+j] : r32[j];
          float send = hi ? r32[j]    : r32[16+j];
          r16[j] = keep + __shfl_xor(send, 16, 64);
      } }
    float r8[8];
    { bool hi = (lane & 8) != 0;
      #pragma unroll
      for (int j = 0; j < 8; ++j) {
          float keep = hi ? r16[8+j] : r16[j];
          float send = hi ? r16[j]   : r16[8+j];
          r8[j] = keep + __shfl_xor(send, 8, 64);
      } }
    float r4[4];
    { bool hi = (lane & 4) != 0;
      #pragma unroll
      for (int j = 0; j < 4; ++j) {
          float keep = hi ? r8[4+j] : r8[j];
          float send = hi ? r8[j]   : r8[4+j];
          r4[j] = keep + __shfl_xor(send, 4, 64);
      } }
    float r2[2];
    { bool hi = (lane & 2) != 0;
      #pragma unroll
      for (int j = 0; j < 2; ++j) {
          float keep = hi ? r4[2+j] : r4[j];
          float send = hi ? r4[j]   : r4[2+j];
          r2[j] = keep + __shfl_xor(send, 2, 64);
      } }
    float r1;
    { bool hi = (lane & 1) != 0;
      float keep = hi ? r2[1] : r2[0];
      float send = hi ? r2[0] : r2[1];
      r1 = keep + __shfl_xor(send, 1, 64);
    }
    red[tid] = r1;                        // tid = wave*64 + lane
    __syncthreads();
    if (tid < 64) {
        float tot = red[tid] + red[tid + 64] + red[tid + 128] + red[tid + 192];
        int slot = (tid < 32) ? (tid << 1) : (((tid - 32) << 1) + 1);
        atomicAdd(&gnsum2[(b << 6) + slot], tot);
    }
}

// ---------------- K5: in-place GroupNorm2 + exact GELU on d_out ----------------------
__global__ __launch_bounds__(256) void k5_final(
    float* __restrict__ out, const float* __restrict__ gnsum2,
    const float* __restrict__ gamma2, const float* __restrict__ beta2) {
    size_t idx = (size_t)blockIdx.x * 256 + threadIdx.x;   // 8388608 threads, 8 elems each
    size_t e8 = idx << 3;
    int b = (int)(e8 >> 25);
    int o = (int)((e8 >> 19) & 63);
    int g = o >> 1;
    float s1 = gnsum2[b*64 + g*2], s2 = gnsum2[b*64 + g*2 + 1];
    const float invn = 1.0f / 1048576.0f;
    float mean = s1 * invn;
    float var  = s2 * invn - mean*mean;
    float rstd = rsqrtf(var + 1e-5f);
    float sc = gamma2[o] * rstd;
    float sf = beta2[o] - mean * sc;
    float4* p0 = (float4*)(out + e8);
    float4 v0 = p0[0], v1 = p0[1];
    float r[8] = {v0.x, v0.y, v0.z, v0.w, v1.x, v1.y, v1.z, v1.w};
    #pragma unroll
    for (int j = 0; j < 8; ++j) {
        float t = fmaf(r[j], sc, sf);
        r[j] = 0.5f * t * (1.0f + erff(t * 0.70710678118654752f));
    }
    p0[0] = make_float4(r[0], r[1], r[2], r[3]);
    p0[1] = make_float4(r[4], r[5], r[6], r[7]);
}

// -------------------------------------------------------------------------------------
extern "C" void kernel_launch(void* const* d_in, const int* in_sizes, int n_in,
                              void* d_out, int out_size, void* d_ws, size_t ws_size,
                              hipStream_t stream) {
    const float* x      = (const float*)d_in[0];
    const float* gridp  = (const float*)d_in[1];
    const float* gamma1 = (const float*)d_in[2];
    const float* beta1  = (const float*)d_in[3];
    const float* w_conv = (const float*)d_in[4];
    const float* sbias  = (const float*)d_in[5];
    const float* w_post = (const float*)d_in[6];
    const float* b_post = (const float*)d_in[7];
    const float* gamma2 = (const float*)d_in[8];
    const float* beta2  = (const float*)d_in[9];
    float* out = (float*)d_out;

    char* ws = (char*)d_ws;
    float* wfold  = (float*)(ws);                                    // 294912 B
    unsigned short* w2b = (unsigned short*)(ws + 294912);            // 294912 B (2 batches)
    float* vb     = (float*)(ws + 589824);                           // 4608 B
    float* gnsum1 = (float*)(ws + 594432);                           // 512 B
    float* gnsum2 = (float*)(ws + 594944);                           // 512 B (contig w/ gnsum1)
    float* acoef  = (float*)(ws + 595456);                           // 1024 B
    float* bcoef  = (float*)(ws + 596480);                           // 1024 B
    float* sb2    = (float*)(ws + 597504);                           // 256 B
    unsigned short* vals = (unsigned short*)(ws + 597760);           // 301,989,888 B
    // total ws needed: 302,587,648 B (~289 MiB)

    hipLaunchKernelGGL(k0_prep,  dim3(290),          dim3(256), 0, stream,
                       w_conv, w_post, sbias, b_post, wfold, sb2, gnsum1);
    hipLaunchKernelGGL(k1_stats, dim3(512),          dim3(256), 0, stream, x, gnsum1);
    hipLaunchKernelGGL(k1b_coef, dim3(1),            dim3(256), 0, stream,
                       gnsum1, gamma1, beta1, acoef, bcoef);
    hipLaunchKernelGGL(k1c_scale, dim3(291, 2),      dim3(256), 0, stream,
                       wfold, acoef, bcoef, w2b, vb);
    hipLaunchKernelGGL(k2_conv,  dim3(1024, 2),      dim3(256), 0, stream,
                       x, w2b, vb, vals);
    hipLaunchKernelGGL(k3_gather, dim3(4, 512, 2),   dim3(256), 0, stream,
                       gridp, vals, sb2, out, gnsum2);
    hipLaunchKernelGGL(k5_final, dim3(32768),        dim3(256), 0, stream,
                       out, gnsum2, gamma2, beta2);
}